// Round 12
// baseline (245.010 us; speedup 1.0000x reference)
//
#include <hip/hip_runtime.h>

typedef __bf16 bf16_t;
typedef __bf16 bf16x8 __attribute__((ext_vector_type(8)));
typedef float f32x4 __attribute__((ext_vector_type(4)));
typedef unsigned short u16;
typedef unsigned short u16x4 __attribute__((ext_vector_type(4)));
typedef unsigned int u32;

#define B_ 4
#define N_ 64
#define P_ 256
#define C_ 384
#define H_ 6
#define D_ 64
#define M_TOTAL 65536
#define NQKV 1152
#define KSTEPS 12                     // 384/32
#define NBLK (H_*B_*N_)               // 1536 = 8 XCDs * 192
#define WKS_U16 10240                 // 20KB per (h,ks): 12 hi frags + 8 lo frags x 1KB
#define WKS_BYTES 20480
// LDS map (u16 offsets):
//   stage bufs (phase 1): 3 x 10240 u16 at 0/10240/20480 (inside dead Kh/Kl region)
//   Kh 0..16384  Kl 16384..32768  Vt 32768..49152     (epilogue onward)
//   per-wave region: 49152 + wid*1024 (16 waves x 2KB)
//     = Q bounce [16][64] (epilogue), then P tile [16][40] (phase 3)
#define FUSED_LDS 131072
#define PB_STRIDE 40
#define SB() __builtin_amdgcn_sched_barrier(0)

#define GLOAD_LDS16(g, l) __builtin_amdgcn_global_load_lds( \
    (const __attribute__((address_space(1))) void*)(g), \
    (__attribute__((address_space(3))) void*)(l), 16, 0, 0)
#define GLOAD_LDS4(g, l) __builtin_amdgcn_global_load_lds( \
    (const __attribute__((address_space(1))) void*)(g), \
    (__attribute__((address_space(3))) void*)(l), 4, 0, 0)

__device__ __forceinline__ u16 f2b(float f){ return __builtin_bit_cast(u16, (bf16_t)f); }
__device__ __forceinline__ f32x4 mfma(bf16x8 a, bf16x8 b, f32x4 c){
    return __builtin_amdgcn_mfma_f32_16x16x32_bf16(a, b, c, 0, 0, 0);
}

// ---------------------------------------------------------------------------
// prep: (a) packed per-(h,ks) 20KB weight blocks [12 hi | 8 lo] fragments
//       (b) w_proj^T bf16    (round-10 version, best measured)
// ---------------------------------------------------------------------------
__global__ __launch_bounds__(256) void prep_w(
    const float* __restrict__ wqkv, const float* __restrict__ wproj,
    u16* __restrict__ Wpk, u16* __restrict__ wPt)
{
    int i = blockIdx.x * 256 + threadIdx.x;
    const int NSLOT = H_ * KSTEPS * 12 * 64;   // 55296
    if (i < NSLOT) {
        int lane = i & 63;
        int frag = i >> 6;
        int nf = frag % 12;
        int ks = (frag / 12) % KSTEPS;
        int h  = frag / (12 * KSTEPS);
        int part = nf >> 2;                        // 0=Q 1=K 2=V
        int nh   = (nf & 3) * 16 + (lane & 15);
        int col  = part * C_ + h * 64 + nh;
        int k0   = ks * 32 + (lane >> 4) * 8;
        size_t base = (size_t)(h * KSTEPS + ks) * WKS_U16;
        #pragma unroll
        for (int e = 0; e < 8; ++e) {
            float w = wqkv[(size_t)(k0 + e) * NQKV + col];
            bf16_t hi = (bf16_t)w;
            Wpk[base + nf * 512 + lane * 8 + e] = __builtin_bit_cast(u16, hi);
            if (nf < 8)
                Wpk[base + 6144 + nf * 512 + lane * 8 + e] = f2b(w - (float)hi);
        }
    }
    int j = i - NSLOT;
    if (j >= 0 && j < C_ * C_) {
        int k = j / C_, n = j % C_;
        wPt[(size_t)n * C_ + k] = f2b(wproj[j]);
    }
}

// ---------------------------------------------------------------------------
// fused per-(h, b*n) kernel: 1024 threads = 16 waves, wave owns 16 q-rows.
// Phase 1: 3-deep weight staging with counted vmcnt + raw s_barrier (r9).
// Phase 2: swapped QK^T (A=K, B=Q) -> lane-local q-row scores (r10);
//   SBs removed (no inline-asm hazard) so K-prefetch can hoist across nf.
// Softmax: exp2 fold (one mul instead of two per element).
// ---------------------------------------------------------------------------
__global__ __launch_bounds__(1024, 4) void fused_attn(
    const float* __restrict__ x, const u16* __restrict__ Wpk,
    u16* __restrict__ attn)
{
    extern __shared__ u16 sm[];
    u16* Kh = sm;              // valid from epilogue (stage bufs live here ph1)
    u16* Kl = sm + 16384;
    u16* Vt = sm + 32768;

    const int tid  = threadIdx.x;
    const int lane = tid & 63, wid = tid >> 6;
    const int g = lane >> 4, r16 = lane & 15;

    // XCD-chunk swizzle (bijective: 1536 = 8 * 192)
    const int p = blockIdx.x;
    const int logical = (p & 7) * (NBLK / 8) + (p >> 3);
    const int h  = logical % H_;
    const int bn = logical / H_;
    const size_t row0 = (size_t)bn * P_;
    const int m0w = wid * 16;

    // ---------------- phase 1: [Q|K|V](16 rows) = X @ W3head, split bf16 ---
    f32x4 acc[12];
    #pragma unroll
    for (int nf = 0; nf < 12; ++nf) acc[nf] = f32x4{0.f,0.f,0.f,0.f};

    const float* xr0 = x + (row0 + m0w + r16) * C_;
    const char* wbase = (const char*)Wpk + (size_t)h * (KSTEPS * WKS_BYTES);

    // uniform staging: every thread issues exactly one 16B + one 4B load
#define STAGE(ks_, b_) do { \
    const char* _gp = wbase + (size_t)(ks_) * WKS_BYTES; \
    char* _lp = (char*)(sm + (b_) * WKS_U16); \
    GLOAD_LDS16(_gp + tid * 16, _lp + tid * 16); \
    GLOAD_LDS4(_gp + 16384 + tid * 4, _lp + 16384 + tid * 4); \
} while (0)

    f32x4 xr[2][2];
#define XLOAD(ks_, par_) do { \
    const float* _xp = xr0 + (ks_) * 32 + 8 * g; \
    xr[par_][0] = *(const f32x4*)_xp; xr[par_][1] = *(const f32x4*)(_xp + 4); \
} while (0)

    bf16x8 ah, al;
#define SPLIT_A(par_) do { \
    _Pragma("unroll") \
    for (int e = 0; e < 4; ++e) { \
        bf16_t h0 = (bf16_t)xr[par_][0][e], h1 = (bf16_t)xr[par_][1][e]; \
        ah[e]   = h0; al[e]   = (bf16_t)(xr[par_][0][e] - (float)h0); \
        ah[4+e] = h1; al[4+e] = (bf16_t)(xr[par_][1][e] - (float)h1); \
    } } while (0)

    // prologue: stage ks=0,1; x(0). vmcnt(2) leaves only x(0) in flight.
    STAGE(0, 0);
    XLOAD(0, 0);
    STAGE(1, 1);
    SB();
    asm volatile("s_waitcnt vmcnt(2)" ::: "memory");
    __builtin_amdgcn_s_barrier();
    SB();

    #pragma unroll
    for (int ks = 0; ks < KSTEPS; ++ks) {
        const int par = ks & 1, nxt = par ^ 1;
        if (ks + 2 < KSTEPS) STAGE(ks + 2, (ks + 2) % 3);   // 2 loads
        if (ks + 1 < KSTEPS) XLOAD(ks + 1, nxt);            // 2 loads
        SPLIT_A(par);

        const u16* stg = sm + (ks % 3) * WKS_U16;
        #pragma unroll
        for (int nf = 0; nf < 8; ++nf) {    // Q,K: split 3x
            bf16x8 bh = *(const bf16x8*)&stg[nf * 512 + lane * 8];
            bf16x8 bl = *(const bf16x8*)&stg[6144 + nf * 512 + lane * 8];
            acc[nf] = mfma(ah, bh, acc[nf]);
            acc[nf] = mfma(ah, bl, acc[nf]);
            acc[nf] = mfma(al, bh, acc[nf]);
        }
        #pragma unroll
        for (int nf = 8; nf < 12; ++nf) {   // V: plain
            bf16x8 bh = *(const bf16x8*)&stg[nf * 512 + lane * 8];
            acc[nf] = mfma(ah, bh, acc[nf]);
        }

        if (ks < KSTEPS - 1) {
            // counted drain: allow stage(ks+2) + x(ks+1) (4 youngest) to fly;
            // forces stage(ks+1) complete. Tail ks=10: only x(11) in flight.
            SB();
            if (ks + 2 < KSTEPS) asm volatile("s_waitcnt vmcnt(4)" ::: "memory");
            else                 asm volatile("s_waitcnt vmcnt(2)" ::: "memory");
            __builtin_amdgcn_s_barrier();
            SB();
        } else {
            __syncthreads();   // full drain: stage region reused as Kh/Kl next
        }
    }

    // ---- epilogue: K -> Kh/Kl (split), V -> Vt (b64-packed), swizzled ----
    #pragma unroll
    for (int f = 0; f < 4; ++f) {
        const int d = f * 16 + r16;
        const int q0 = m0w + 4 * g;
        u16x4 vv;
        #pragma unroll
        for (int rr = 0; rr < 4; ++rr) vv[rr] = f2b(acc[8 + f][rr]);
        *(u16x4*)&Vt[d * 256 + (((q0 >> 3) ^ (d & 7)) << 3) + (q0 & 7)] = vv;
        #pragma unroll
        for (int rr = 0; rr < 4; ++rr) {
            int q = q0 + rr;
            int ek = q * 64 + (((d >> 3) ^ (q & 7)) << 3) + (d & 7);
            float kv = acc[4 + f][rr];
            bf16_t khi = (bf16_t)kv;
            Kh[ek] = __builtin_bit_cast(u16, khi);
            Kl[ek] = f2b(kv - (float)khi);
        }
    }

    // ---- Q bounce (per-wave region, two passes hi/lo) ----
    u16* myQb = sm + 49152 + wid * 1024;   // [16][64] swizzled
    bf16x8 aqh[2], aql[2];
    #pragma unroll
    for (int f = 0; f < 4; ++f)
    #pragma unroll
    for (int rr = 0; rr < 4; ++rr) {
        int r = 4 * g + rr;
        int c = f * 16 + r16;
        myQb[r * 64 + (((c >> 3) ^ (r & 7)) << 3) + (c & 7)] = f2b(acc[f][rr]);
    }
    #pragma unroll
    for (int k2 = 0; k2 < 2; ++k2)
        aqh[k2] = *(const bf16x8*)&myQb[r16 * 64 + (((k2 * 4 + g) ^ (r16 & 7)) << 3)];
    SB();   // keep lo-pass writes after hi-pass reads
    #pragma unroll
    for (int f = 0; f < 4; ++f)
    #pragma unroll
    for (int rr = 0; rr < 4; ++rr) {
        int r = 4 * g + rr;
        int c = f * 16 + r16;
        float v = acc[f][rr];
        bf16_t hi = (bf16_t)v;
        myQb[r * 64 + (((c >> 3) ^ (r & 7)) << 3) + (c & 7)] = f2b(v - (float)hi);
    }
    #pragma unroll
    for (int k2 = 0; k2 < 2; ++k2)
        aql[k2] = *(const bf16x8*)&myQb[r16 * 64 + (((k2 * 4 + g) ^ (r16 & 7)) << 3)];

    __syncthreads();   // Kh/Kl/Vt visible block-wide

    // ---------------- phase 2: S^T = K Q^T (swapped operands, split 3x) ----
    // C-layout: lane (g,r16), reg rr holds S[q = m0w+r16][key = 16nf+4g+rr].
    f32x4 S[16];
    #pragma unroll
    for (int nf = 0; nf < 16; ++nf) S[nf] = f32x4{0.f,0.f,0.f,0.f};

    const int kb0 = r16 * 64 + (((0 * 4 + g) ^ (r16 & 7)) << 3);
    const int kb1 = r16 * 64 + (((1 * 4 + g) ^ (r16 & 7)) << 3);

    bf16x8 khv[2][2], klv[2][2];
    {
        khv[0][0] = *(const bf16x8*)&Kh[kb0];
        klv[0][0] = *(const bf16x8*)&Kl[kb0];
        khv[0][1] = *(const bf16x8*)&Kh[kb1];
        klv[0][1] = *(const bf16x8*)&Kl[kb1];
    }
    #pragma unroll
    for (int nf = 0; nf < 16; ++nf) {
        const int par = nf & 1, nxt = par ^ 1;
        if (nf < 15) {
            const int o = (nf + 1) * 1024;
            khv[nxt][0] = *(const bf16x8*)&Kh[o + kb0];
            klv[nxt][0] = *(const bf16x8*)&Kl[o + kb0];
            khv[nxt][1] = *(const bf16x8*)&Kh[o + kb1];
            klv[nxt][1] = *(const bf16x8*)&Kl[o + kb1];
        }
        __builtin_amdgcn_s_setprio(1);
        #pragma unroll
        for (int k2 = 0; k2 < 2; ++k2) {
            S[nf] = mfma(khv[par][k2], aqh[k2], S[nf]);   // kh*qh
            S[nf] = mfma(klv[par][k2], aqh[k2], S[nf]);   // kl*qh
            S[nf] = mfma(khv[par][k2], aql[k2], S[nf]);   // kh*ql
        }
        __builtin_amdgcn_s_setprio(0);
    }

    // ---------------- softmax: each lane owns one q-row's 64 samples -------
    // exp(64*(S-m)) = exp2((S-m) * 64*log2(e))
    float inv_;
    {
        float m = -1e30f;
        #pragma unroll
        for (int nf = 0; nf < 16; ++nf)
            #pragma unroll
            for (int rr = 0; rr < 4; ++rr) m = fmaxf(m, S[nf][rr]);
        m = fmaxf(m, __shfl_xor(m, 16, 64));
        m = fmaxf(m, __shfl_xor(m, 32, 64));
        float s = 0.f;
        #pragma unroll
        for (int nf = 0; nf < 16; ++nf)
            #pragma unroll
            for (int rr = 0; rr < 4; ++rr) {
                float pv = exp2f((S[nf][rr] - m) * 92.33248261689366f);
                S[nf][rr] = pv;
                s += pv;
            }
        s += __shfl_xor(s, 16, 64);
        s += __shfl_xor(s, 32, 64);
        inv_ = 1.0f / s;
    }

    // ---------------- phase 3: O = P V (packed b64 P-bounce) ---------------
    f32x4 O[4];
    #pragma unroll
    for (int f = 0; f < 4; ++f) O[f] = f32x4{0.f,0.f,0.f,0.f};

    u16* pt = sm + 49152 + wid * 1024;       // reuse Q-bounce region: [16][40]
    const int vc = r16 & 7;
    #pragma unroll
    for (int t = 0; t < 8; ++t) {
        bf16x8 bv[4];
        const int vo = (((4 * t + g) ^ vc) << 3) + r16 * 256;
        #pragma unroll
        for (int f = 0; f < 4; ++f)
            bv[f] = *(const bf16x8*)&Vt[f * 4096 + vo];
        #pragma unroll
        for (int nu = 0; nu < 2; ++nu) {
            int nf = 2 * t + nu;
            u16x4 pk;
            #pragma unroll
            for (int rr = 0; rr < 4; ++rr) pk[rr] = f2b(S[nf][rr] * inv_);
            *(u16x4*)&pt[r16 * PB_STRIDE + nu * 16 + 4 * g] = pk;
        }
        bf16x8 ap = *(const bf16x8*)&pt[r16 * PB_STRIDE + 8 * g];
        __builtin_amdgcn_s_setprio(1);
        #pragma unroll
        for (int f = 0; f < 4; ++f) O[f] = mfma(ap, bv[f], O[f]);
        __builtin_amdgcn_s_setprio(0);
    }

    #pragma unroll
    for (int f = 0; f < 4; ++f)
    #pragma unroll
    for (int rr = 0; rr < 4; ++rr)
        attn[(row0 + m0w + 4 * g + rr) * C_ + h * 64 + f * 16 + r16] = f2b(O[f][rr]);
}

// ---------------------------------------------------------------------------
// proj (round-10 version): attn(65536x384 bf16) @ w_proj(384x384) + bias.
// ---------------------------------------------------------------------------
__global__ __launch_bounds__(256, 2) void proj_kernel(
    const u16* __restrict__ attn, const u16* __restrict__ wPt,
    const float* __restrict__ bias, float* __restrict__ out)
{
    __shared__ alignas(16) u16 As[128*32];
    __shared__ alignas(16) u16 Bs[128*32];

    const int tid = threadIdx.x;
    const int lane = tid & 63, wid = tid >> 6;
    const int wr = wid >> 1, wc = wid & 1;
    const int g = lane >> 4, r16 = lane & 15;
    const int m0 = blockIdx.x * 128;
    const int n0 = blockIdx.y * 128;

    f32x4 acc[4][4];
    for (int i = 0; i < 4; i++) for (int j = 0; j < 4; j++) acc[i][j] = f32x4{0.f,0.f,0.f,0.f};

    for (int kt = 0; kt < C_; kt += 32) {
        for (int r = 0; r < 4; ++r) {
            int i = tid + 256*r;
            int mm = i >> 3;
            int kk = (i & 7) << 2;
            u16x4 v = *(const u16x4*)&attn[(size_t)(m0+mm)*C_ + kt + kk];
            int e = mm*32 + (((kk>>3) ^ ((mm>>1)&3))<<3) + (kk&7);
            *(u16x4*)&As[e] = v;
        }
        for (int r = 0; r < 4; ++r) {
            int i = tid + 256*r;
            int nn = i >> 3;
            int kk = (i & 7) << 2;
            u16x4 v = *(const u16x4*)&wPt[(size_t)(n0+nn)*C_ + kt + kk];
            int e = nn*32 + (((kk>>3) ^ ((nn>>1)&3))<<3) + (kk&7);
            *(u16x4*)&Bs[e] = v;
        }
        __syncthreads();

        bf16x8 a[4], b[4];
        for (int i = 0; i < 4; i++) {
            int row = wr*64 + i*16 + r16;
            a[i] = *(const bf16x8*)&As[row*32 + ((g ^ ((row>>1)&3))<<3)];
        }
        for (int j = 0; j < 4; j++) {
            int n = wc*64 + j*16 + r16;
            b[j] = *(const bf16x8*)&Bs[n*32 + ((g ^ ((n>>1)&3))<<3)];
        }
        for (int i = 0; i < 4; i++) for (int j = 0; j < 4; j++)
            acc[i][j] = mfma(a[i], b[j], acc[i][j]);
        __syncthreads();
    }

    for (int i = 0; i < 4; i++) for (int j = 0; j < 4; j++) for (int rr = 0; rr < 4; rr++) {
        size_t row = m0 + wr*64 + i*16 + g*4 + rr;
        int col = n0 + wc*64 + j*16 + r16;
        out[row*C_ + col] = acc[i][j][rr] + bias[col];
    }
}

// ---------------------------------------------------------------------------
extern "C" void kernel_launch(void* const* d_in, const int* in_sizes, int n_in,
                              void* d_out, int out_size, void* d_ws, size_t ws_size,
                              hipStream_t stream)
{
    const float* x      = (const float*)d_in[0];
    const float* w_qkv  = (const float*)d_in[1];
    const float* w_proj = (const float*)d_in[2];
    const float* b_proj = (const float*)d_in[3];
    float* out = (float*)d_out;

    u16* ws = (u16*)d_ws;
    u16* attnb = ws;                                  // 65536*384 u16 = 50 MB
    size_t off = (size_t)M_TOTAL * C_;
    u16* Wpk = ws + off; off += (size_t)H_ * KSTEPS * WKS_U16;
    u16* wPt = ws + off; off += (size_t)C_ * C_;

    hipFuncSetAttribute((const void*)fused_attn,
                        hipFuncAttributeMaxDynamicSharedMemorySize, FUSED_LDS);

    int prep_n = H_ * KSTEPS * 12 * 64 + C_ * C_;
    prep_w<<<dim3((prep_n + 255) / 256), 256, 0, stream>>>(w_qkv, w_proj, Wpk, wPt);
    fused_attn<<<dim3(NBLK), 1024, FUSED_LDS, stream>>>(x, Wpk, attnb);
    proj_kernel<<<dim3(M_TOTAL / 128, C_ / 128), 256, 0, stream>>>(attnb, wPt, b_proj, out);
}

// Round 14
// 243.275 us; speedup vs baseline: 1.0071x; 1.0071x over previous
//
#include <hip/hip_runtime.h>

typedef __bf16 bf16_t;
typedef __bf16 bf16x8 __attribute__((ext_vector_type(8)));
typedef float f32x4 __attribute__((ext_vector_type(4)));
typedef unsigned short u16;
typedef unsigned short u16x4 __attribute__((ext_vector_type(4)));
typedef unsigned int u32;

#define B_ 4
#define N_ 64
#define P_ 256
#define C_ 384
#define H_ 6
#define D_ 64
#define M_TOTAL 65536
#define NQKV 1152
#define KSTEPS 12                     // 384/32
#define NBLK (H_*B_*N_)               // 1536 = 8 XCDs * 192
#define WKS_U16 10240                 // 20KB per (h,ks): 12 hi frags + 8 lo frags x 1KB
#define WKS_BYTES 20480
// LDS map (u16 offsets):
//   stage bufs (phase 1): 3 x 10240 u16 at 0/10240/20480 (inside dead Kh/Kl region)
//   Kh 0..16384  Kl 16384..32768  Vt 32768..49152     (epilogue onward)
//   per-wave region: 49152 + wid*1024 (16 waves x 2KB)
//     = Q bounce [16][64] (epilogue), then P tile [16][40] (phase 3)
#define FUSED_LDS 131072
#define PB_STRIDE 40
#define SB() __builtin_amdgcn_sched_barrier(0)

#define GLOAD_LDS16(g, l) __builtin_amdgcn_global_load_lds( \
    (const __attribute__((address_space(1))) void*)(g), \
    (__attribute__((address_space(3))) void*)(l), 16, 0, 0)
#define GLOAD_LDS4(g, l) __builtin_amdgcn_global_load_lds( \
    (const __attribute__((address_space(1))) void*)(g), \
    (__attribute__((address_space(3))) void*)(l), 4, 0, 0)

__device__ __forceinline__ u16 f2b(float f){ return __builtin_bit_cast(u16, (bf16_t)f); }
__device__ __forceinline__ f32x4 mfma(bf16x8 a, bf16x8 b, f32x4 c){
    return __builtin_amdgcn_mfma_f32_16x16x32_bf16(a, b, c, 0, 0, 0);
}

// ---------------------------------------------------------------------------
// prep: (a) packed per-(h,ks) 20KB weight blocks [12 hi | 8 lo] fragments
//       (b) w_proj^T bf16    (round-10 version, best measured)
// ---------------------------------------------------------------------------
__global__ __launch_bounds__(256) void prep_w(
    const float* __restrict__ wqkv, const float* __restrict__ wproj,
    u16* __restrict__ Wpk, u16* __restrict__ wPt)
{
    int i = blockIdx.x * 256 + threadIdx.x;
    const int NSLOT = H_ * KSTEPS * 12 * 64;   // 55296
    if (i < NSLOT) {
        int lane = i & 63;
        int frag = i >> 6;
        int nf = frag % 12;
        int ks = (frag / 12) % KSTEPS;
        int h  = frag / (12 * KSTEPS);
        int part = nf >> 2;                        // 0=Q 1=K 2=V
        int nh   = (nf & 3) * 16 + (lane & 15);
        int col  = part * C_ + h * 64 + nh;
        int k0   = ks * 32 + (lane >> 4) * 8;
        size_t base = (size_t)(h * KSTEPS + ks) * WKS_U16;
        #pragma unroll
        for (int e = 0; e < 8; ++e) {
            float w = wqkv[(size_t)(k0 + e) * NQKV + col];
            bf16_t hi = (bf16_t)w;
            Wpk[base + nf * 512 + lane * 8 + e] = __builtin_bit_cast(u16, hi);
            if (nf < 8)
                Wpk[base + 6144 + nf * 512 + lane * 8 + e] = f2b(w - (float)hi);
        }
    }
    int j = i - NSLOT;
    if (j >= 0 && j < C_ * C_) {
        int k = j / C_, n = j % C_;
        wPt[(size_t)n * C_ + k] = f2b(wproj[j]);
    }
}

// ---------------------------------------------------------------------------
// fused per-(h, b*n) kernel: 1024 threads = 16 waves, wave owns 16 q-rows.
// = round-10 structure + exp2-folded softmax + deferred normalization.
// r13 bug fixed: inv_ belongs to q-row r16 (S^T lane layout) but O's reg rr
// maps to q-row 4g+rr -- gather the right normalizer via __shfl from lane
// 4g+rr before the final store.
// ---------------------------------------------------------------------------
__global__ __launch_bounds__(1024, 4) void fused_attn(
    const float* __restrict__ x, const u16* __restrict__ Wpk,
    u16* __restrict__ attn)
{
    extern __shared__ u16 sm[];
    u16* Kh = sm;              // valid from epilogue (stage bufs live here ph1)
    u16* Kl = sm + 16384;
    u16* Vt = sm + 32768;

    const int tid  = threadIdx.x;
    const int lane = tid & 63, wid = tid >> 6;
    const int g = lane >> 4, r16 = lane & 15;

    // XCD-chunk swizzle (bijective: 1536 = 8 * 192)
    const int p = blockIdx.x;
    const int logical = (p & 7) * (NBLK / 8) + (p >> 3);
    const int h  = logical % H_;
    const int bn = logical / H_;
    const size_t row0 = (size_t)bn * P_;
    const int m0w = wid * 16;

    // ---------------- phase 1: [Q|K|V](16 rows) = X @ W3head, split bf16 ---
    f32x4 acc[12];
    #pragma unroll
    for (int nf = 0; nf < 12; ++nf) acc[nf] = f32x4{0.f,0.f,0.f,0.f};

    const float* xr0 = x + (row0 + m0w + r16) * C_;
    const char* wbase = (const char*)Wpk + (size_t)h * (KSTEPS * WKS_BYTES);

    // uniform staging: every thread issues exactly one 16B + one 4B load
#define STAGE(ks_, b_) do { \
    const char* _gp = wbase + (size_t)(ks_) * WKS_BYTES; \
    char* _lp = (char*)(sm + (b_) * WKS_U16); \
    GLOAD_LDS16(_gp + tid * 16, _lp + tid * 16); \
    GLOAD_LDS4(_gp + 16384 + tid * 4, _lp + 16384 + tid * 4); \
} while (0)

    f32x4 xr[2][2];
#define XLOAD(ks_, par_) do { \
    const float* _xp = xr0 + (ks_) * 32 + 8 * g; \
    xr[par_][0] = *(const f32x4*)_xp; xr[par_][1] = *(const f32x4*)(_xp + 4); \
} while (0)

    bf16x8 ah, al;
#define SPLIT_A(par_) do { \
    _Pragma("unroll") \
    for (int e = 0; e < 4; ++e) { \
        bf16_t h0 = (bf16_t)xr[par_][0][e], h1 = (bf16_t)xr[par_][1][e]; \
        ah[e]   = h0; al[e]   = (bf16_t)(xr[par_][0][e] - (float)h0); \
        ah[4+e] = h1; al[4+e] = (bf16_t)(xr[par_][1][e] - (float)h1); \
    } } while (0)

    // prologue: stage ks=0,1; x(0). vmcnt(2) leaves only stage(1) in flight.
    STAGE(0, 0);
    XLOAD(0, 0);
    STAGE(1, 1);
    SB();
    asm volatile("s_waitcnt vmcnt(2)" ::: "memory");
    __builtin_amdgcn_s_barrier();
    SB();

    #pragma unroll
    for (int ks = 0; ks < KSTEPS; ++ks) {
        const int par = ks & 1, nxt = par ^ 1;
        if (ks + 2 < KSTEPS) STAGE(ks + 2, (ks + 2) % 3);   // 2 loads
        if (ks + 1 < KSTEPS) XLOAD(ks + 1, nxt);            // 2 loads
        SPLIT_A(par);

        const u16* stg = sm + (ks % 3) * WKS_U16;
        #pragma unroll
        for (int nf = 0; nf < 8; ++nf) {    // Q,K: split 3x
            bf16x8 bh = *(const bf16x8*)&stg[nf * 512 + lane * 8];
            bf16x8 bl = *(const bf16x8*)&stg[6144 + nf * 512 + lane * 8];
            acc[nf] = mfma(ah, bh, acc[nf]);
            acc[nf] = mfma(ah, bl, acc[nf]);
            acc[nf] = mfma(al, bh, acc[nf]);
        }
        #pragma unroll
        for (int nf = 8; nf < 12; ++nf) {   // V: plain
            bf16x8 bh = *(const bf16x8*)&stg[nf * 512 + lane * 8];
            acc[nf] = mfma(ah, bh, acc[nf]);
        }

        if (ks < KSTEPS - 1) {
            // counted drain: allow stage(ks+2) + x(ks+1) (4 youngest) to fly;
            // forces stage(ks+1) complete. Tail ks=10: only x(11) in flight.
            SB();
            if (ks + 2 < KSTEPS) asm volatile("s_waitcnt vmcnt(4)" ::: "memory");
            else                 asm volatile("s_waitcnt vmcnt(2)" ::: "memory");
            __builtin_amdgcn_s_barrier();
            SB();
        } else {
            __syncthreads();   // full drain: stage region reused as Kh/Kl next
        }
    }

    // ---- epilogue: K -> Kh/Kl (split), V -> Vt (b64-packed), swizzled ----
    #pragma unroll
    for (int f = 0; f < 4; ++f) {
        const int d = f * 16 + r16;
        const int q0 = m0w + 4 * g;
        u16x4 vv;
        #pragma unroll
        for (int rr = 0; rr < 4; ++rr) vv[rr] = f2b(acc[8 + f][rr]);
        *(u16x4*)&Vt[d * 256 + (((q0 >> 3) ^ (d & 7)) << 3) + (q0 & 7)] = vv;
        #pragma unroll
        for (int rr = 0; rr < 4; ++rr) {
            int q = q0 + rr;
            int ek = q * 64 + (((d >> 3) ^ (q & 7)) << 3) + (d & 7);
            float kv = acc[4 + f][rr];
            bf16_t khi = (bf16_t)kv;
            Kh[ek] = __builtin_bit_cast(u16, khi);
            Kl[ek] = f2b(kv - (float)khi);
        }
    }

    // ---- Q bounce (per-wave region, two passes hi/lo) ----
    u16* myQb = sm + 49152 + wid * 1024;   // [16][64] swizzled
    bf16x8 aqh[2], aql[2];
    #pragma unroll
    for (int f = 0; f < 4; ++f)
    #pragma unroll
    for (int rr = 0; rr < 4; ++rr) {
        int r = 4 * g + rr;
        int c = f * 16 + r16;
        myQb[r * 64 + (((c >> 3) ^ (r & 7)) << 3) + (c & 7)] = f2b(acc[f][rr]);
    }
    #pragma unroll
    for (int k2 = 0; k2 < 2; ++k2)
        aqh[k2] = *(const bf16x8*)&myQb[r16 * 64 + (((k2 * 4 + g) ^ (r16 & 7)) << 3)];
    SB();   // keep lo-pass writes after hi-pass reads
    #pragma unroll
    for (int f = 0; f < 4; ++f)
    #pragma unroll
    for (int rr = 0; rr < 4; ++rr) {
        int r = 4 * g + rr;
        int c = f * 16 + r16;
        float v = acc[f][rr];
        bf16_t hi = (bf16_t)v;
        myQb[r * 64 + (((c >> 3) ^ (r & 7)) << 3) + (c & 7)] = f2b(v - (float)hi);
    }
    #pragma unroll
    for (int k2 = 0; k2 < 2; ++k2)
        aql[k2] = *(const bf16x8*)&myQb[r16 * 64 + (((k2 * 4 + g) ^ (r16 & 7)) << 3)];

    __syncthreads();   // Kh/Kl/Vt visible block-wide

    // ---------------- phase 2: S^T = K Q^T (swapped operands, split 3x) ----
    // C-layout: lane (g,r16), reg rr holds S[q = m0w+r16][key = 16nf+4g+rr].
    f32x4 S[16];
    #pragma unroll
    for (int nf = 0; nf < 16; ++nf) S[nf] = f32x4{0.f,0.f,0.f,0.f};

    const int kb0 = r16 * 64 + (((0 * 4 + g) ^ (r16 & 7)) << 3);
    const int kb1 = r16 * 64 + (((1 * 4 + g) ^ (r16 & 7)) << 3);

    bf16x8 khv[2][2], klv[2][2];
    {
        khv[0][0] = *(const bf16x8*)&Kh[kb0];
        klv[0][0] = *(const bf16x8*)&Kl[kb0];
        khv[0][1] = *(const bf16x8*)&Kh[kb1];
        klv[0][1] = *(const bf16x8*)&Kl[kb1];
    }
    #pragma unroll
    for (int nf = 0; nf < 16; ++nf) {
        const int par = nf & 1, nxt = par ^ 1;
        if (nf < 15) {
            const int o = (nf + 1) * 1024;
            khv[nxt][0] = *(const bf16x8*)&Kh[o + kb0];
            klv[nxt][0] = *(const bf16x8*)&Kl[o + kb0];
            khv[nxt][1] = *(const bf16x8*)&Kh[o + kb1];
            klv[nxt][1] = *(const bf16x8*)&Kl[o + kb1];
        }
        SB();
        __builtin_amdgcn_s_setprio(1);
        #pragma unroll
        for (int k2 = 0; k2 < 2; ++k2) {
            S[nf] = mfma(khv[par][k2], aqh[k2], S[nf]);   // kh*qh
            S[nf] = mfma(klv[par][k2], aqh[k2], S[nf]);   // kl*qh
            S[nf] = mfma(khv[par][k2], aql[k2], S[nf]);   // kh*ql
        }
        __builtin_amdgcn_s_setprio(0);
        SB();
    }

    // ---------------- softmax: each lane owns one q-row's 64 samples -------
    // exp(64*(S-m)) = exp2((S-m) * 64*log2(e)); normalization deferred to O.
    float inv_;
    {
        float m = -1e30f;
        #pragma unroll
        for (int nf = 0; nf < 16; ++nf)
            #pragma unroll
            for (int rr = 0; rr < 4; ++rr) m = fmaxf(m, S[nf][rr]);
        m = fmaxf(m, __shfl_xor(m, 16, 64));
        m = fmaxf(m, __shfl_xor(m, 32, 64));
        float s = 0.f;
        #pragma unroll
        for (int nf = 0; nf < 16; ++nf)
            #pragma unroll
            for (int rr = 0; rr < 4; ++rr) {
                float pv = exp2f((S[nf][rr] - m) * 92.33248261689366f);
                S[nf][rr] = pv;
                s += pv;
            }
        s += __shfl_xor(s, 16, 64);
        s += __shfl_xor(s, 32, 64);
        inv_ = 1.0f / s;
    }
    // normalizer for O's row layout (row = 4g+rr lives in lane 4g+rr's inv_)
    float inv_o[4];
    #pragma unroll
    for (int rr = 0; rr < 4; ++rr)
        inv_o[rr] = __shfl(inv_, 4 * g + rr, 64);

    // ---------------- phase 3: O = P V (packed b64 P-bounce, raw P) --------
    f32x4 O[4];
    #pragma unroll
    for (int f = 0; f < 4; ++f) O[f] = f32x4{0.f,0.f,0.f,0.f};

    u16* pt = sm + 49152 + wid * 1024;       // reuse Q-bounce region: [16][40]
    const int vc = r16 & 7;
    #pragma unroll
    for (int t = 0; t < 8; ++t) {
        bf16x8 bv[4];
        const int vo = (((4 * t + g) ^ vc) << 3) + r16 * 256;
        #pragma unroll
        for (int f = 0; f < 4; ++f)
            bv[f] = *(const bf16x8*)&Vt[f * 4096 + vo];
        #pragma unroll
        for (int nu = 0; nu < 2; ++nu) {
            int nf = 2 * t + nu;
            u16x4 pk;
            #pragma unroll
            for (int rr = 0; rr < 4; ++rr) pk[rr] = f2b(S[nf][rr]);
            *(u16x4*)&pt[r16 * PB_STRIDE + nu * 16 + 4 * g] = pk;
        }
        bf16x8 ap = *(const bf16x8*)&pt[r16 * PB_STRIDE + 8 * g];
        __builtin_amdgcn_s_setprio(1);
        #pragma unroll
        for (int f = 0; f < 4; ++f) O[f] = mfma(ap, bv[f], O[f]);
        __builtin_amdgcn_s_setprio(0);
    }

    #pragma unroll
    for (int f = 0; f < 4; ++f)
    #pragma unroll
    for (int rr = 0; rr < 4; ++rr)
        attn[(row0 + m0w + 4 * g + rr) * C_ + h * 64 + f * 16 + r16] = f2b(O[f][rr] * inv_o[rr]);
}

// ---------------------------------------------------------------------------
// proj (round-10 version): attn(65536x384 bf16) @ w_proj(384x384) + bias.
// ---------------------------------------------------------------------------
__global__ __launch_bounds__(256, 2) void proj_kernel(
    const u16* __restrict__ attn, const u16* __restrict__ wPt,
    const float* __restrict__ bias, float* __restrict__ out)
{
    __shared__ alignas(16) u16 As[128*32];
    __shared__ alignas(16) u16 Bs[128*32];

    const int tid = threadIdx.x;
    const int lane = tid & 63, wid = tid >> 6;
    const int wr = wid >> 1, wc = wid & 1;
    const int g = lane >> 4, r16 = lane & 15;
    const int m0 = blockIdx.x * 128;
    const int n0 = blockIdx.y * 128;

    f32x4 acc[4][4];
    for (int i = 0; i < 4; i++) for (int j = 0; j < 4; j++) acc[i][j] = f32x4{0.f,0.f,0.f,0.f};

    for (int kt = 0; kt < C_; kt += 32) {
        for (int r = 0; r < 4; ++r) {
            int i = tid + 256*r;
            int mm = i >> 3;
            int kk = (i & 7) << 2;
            u16x4 v = *(const u16x4*)&attn[(size_t)(m0+mm)*C_ + kt + kk];
            int e = mm*32 + (((kk>>3) ^ ((mm>>1)&3))<<3) + (kk&7);
            *(u16x4*)&As[e] = v;
        }
        for (int r = 0; r < 4; ++r) {
            int i = tid + 256*r;
            int nn = i >> 3;
            int kk = (i & 7) << 2;
            u16x4 v = *(const u16x4*)&wPt[(size_t)(n0+nn)*C_ + kt + kk];
            int e = nn*32 + (((kk>>3) ^ ((nn>>1)&3))<<3) + (kk&7);
            *(u16x4*)&Bs[e] = v;
        }
        __syncthreads();

        bf16x8 a[4], b[4];
        for (int i = 0; i < 4; i++) {
            int row = wr*64 + i*16 + r16;
            a[i] = *(const bf16x8*)&As[row*32 + ((g ^ ((row>>1)&3))<<3)];
        }
        for (int j = 0; j < 4; j++) {
            int n = wc*64 + j*16 + r16;
            b[j] = *(const bf16x8*)&Bs[n*32 + ((g ^ ((n>>1)&3))<<3)];
        }
        for (int i = 0; i < 4; i++) for (int j = 0; j < 4; j++)
            acc[i][j] = mfma(a[i], b[j], acc[i][j]);
        __syncthreads();
    }

    for (int i = 0; i < 4; i++) for (int j = 0; j < 4; j++) for (int rr = 0; rr < 4; rr++) {
        size_t row = m0 + wr*64 + i*16 + g*4 + rr;
        int col = n0 + wc*64 + j*16 + r16;
        out[row*C_ + col] = acc[i][j][rr] + bias[col];
    }
}

// ---------------------------------------------------------------------------
extern "C" void kernel_launch(void* const* d_in, const int* in_sizes, int n_in,
                              void* d_out, int out_size, void* d_ws, size_t ws_size,
                              hipStream_t stream)
{
    const float* x      = (const float*)d_in[0];
    const float* w_qkv  = (const float*)d_in[1];
    const float* w_proj = (const float*)d_in[2];
    const float* b_proj = (const float*)d_in[3];
    float* out = (float*)d_out;

    u16* ws = (u16*)d_ws;
    u16* attnb = ws;                                  // 65536*384 u16 = 50 MB
    size_t off = (size_t)M_TOTAL * C_;
    u16* Wpk = ws + off; off += (size_t)H_ * KSTEPS * WKS_U16;
    u16* wPt = ws + off; off += (size_t)C_ * C_;

    hipFuncSetAttribute((const void*)fused_attn,
                        hipFuncAttributeMaxDynamicSharedMemorySize, FUSED_LDS);

    int prep_n = H_ * KSTEPS * 12 * 64 + C_ * C_;
    prep_w<<<dim3((prep_n + 255) / 256), 256, 0, stream>>>(w_qkv, w_proj, Wpk, wPt);
    fused_attn<<<dim3(NBLK), 1024, FUSED_LDS, stream>>>(x, Wpk, attnb);
    proj_kernel<<<dim3(M_TOTAL / 128, C_ / 128), 256, 0, stream>>>(attnb, wPt, b_proj, out);
}

// Round 15
// 237.407 us; speedup vs baseline: 1.0320x; 1.0247x over previous
//
#include <hip/hip_runtime.h>

typedef __bf16 bf16_t;
typedef __bf16 bf16x8 __attribute__((ext_vector_type(8)));
typedef float f32x4 __attribute__((ext_vector_type(4)));
typedef unsigned short u16;
typedef unsigned short u16x4 __attribute__((ext_vector_type(4)));
typedef unsigned int u32;

#define B_ 4
#define N_ 64
#define P_ 256
#define C_ 384
#define H_ 6
#define D_ 64
#define M_TOTAL 65536
#define NQKV 1152
#define KSTEPS 12                     // 384/32
#define NBLK (H_*B_*N_)               // 1536 = 8 XCDs * 192
#define WKS_U16 10240                 // 20KB per (h,ks): 12 hi frags + 8 lo frags x 1KB
#define WKS_BYTES 20480
// LDS map (u16 offsets):
//   stage bufs (phase 1): 3 x 10240 u16 at 0/10240/20480 (inside dead Kh/Kl region)
//   Kh 0..16384  Kl 16384..32768  Vt 32768..49152     (epilogue onward)
//   per-wave region: 49152 + wid*1024 (16 waves x 2KB)
//     = Q bounce [16][64] (epilogue), then P tile [16][40] (phase 3)
#define FUSED_LDS 131072
#define PB_STRIDE 40
#define SB() __builtin_amdgcn_sched_barrier(0)

#define GLOAD_LDS16(g, l) __builtin_amdgcn_global_load_lds( \
    (const __attribute__((address_space(1))) void*)(g), \
    (__attribute__((address_space(3))) void*)(l), 16, 0, 0)
#define GLOAD_LDS4(g, l) __builtin_amdgcn_global_load_lds( \
    (const __attribute__((address_space(1))) void*)(g), \
    (__attribute__((address_space(3))) void*)(l), 4, 0, 0)

__device__ __forceinline__ u16 f2b(float f){ return __builtin_bit_cast(u16, (bf16_t)f); }
__device__ __forceinline__ f32x4 mfma(bf16x8 a, bf16x8 b, f32x4 c){
    return __builtin_amdgcn_mfma_f32_16x16x32_bf16(a, b, c, 0, 0, 0);
}

// ---------------------------------------------------------------------------
// prep: (a) packed per-(h,ks) 20KB weight blocks [12 hi | 8 lo] fragments
//       (b) w_proj^T bf16
// ---------------------------------------------------------------------------
__global__ __launch_bounds__(256) void prep_w(
    const float* __restrict__ wqkv, const float* __restrict__ wproj,
    u16* __restrict__ Wpk, u16* __restrict__ wPt)
{
    int i = blockIdx.x * 256 + threadIdx.x;
    const int NSLOT = H_ * KSTEPS * 12 * 64;   // 55296
    if (i < NSLOT) {
        int lane = i & 63;
        int frag = i >> 6;
        int nf = frag % 12;
        int ks = (frag / 12) % KSTEPS;
        int h  = frag / (12 * KSTEPS);
        int part = nf >> 2;                        // 0=Q 1=K 2=V
        int nh   = (nf & 3) * 16 + (lane & 15);
        int col  = part * C_ + h * 64 + nh;
        int k0   = ks * 32 + (lane >> 4) * 8;
        size_t base = (size_t)(h * KSTEPS + ks) * WKS_U16;
        #pragma unroll
        for (int e = 0; e < 8; ++e) {
            float w = wqkv[(size_t)(k0 + e) * NQKV + col];
            bf16_t hi = (bf16_t)w;
            Wpk[base + nf * 512 + lane * 8 + e] = __builtin_bit_cast(u16, hi);
            if (nf < 8)
                Wpk[base + 6144 + nf * 512 + lane * 8 + e] = f2b(w - (float)hi);
        }
    }
    int j = i - NSLOT;
    if (j >= 0 && j < C_ * C_) {
        int k = j / C_, n = j % C_;
        wPt[(size_t)n * C_ + k] = f2b(wproj[j]);
    }
}

// ---------------------------------------------------------------------------
// fused per-(h, b*n) kernel: 1024 threads = 16 waves, wave owns 16 q-rows.
// Phase 1: 3-deep weight staging with counted vmcnt + raw s_barrier.
// Phase 2: swapped QK^T (A=K, B=Q) -> lane-local q-row scores; softmax =
//   in-lane reduce + 2 shuffles; P-bounce = 2 packed b64 writes + 1 b128
//   read per PV tile. (Exact round-10 configuration — best measured.)
// ---------------------------------------------------------------------------
__global__ __launch_bounds__(1024, 4) void fused_attn(
    const float* __restrict__ x, const u16* __restrict__ Wpk,
    u16* __restrict__ attn)
{
    extern __shared__ u16 sm[];
    u16* Kh = sm;              // valid from epilogue (stage bufs live here ph1)
    u16* Kl = sm + 16384;
    u16* Vt = sm + 32768;

    const int tid  = threadIdx.x;
    const int lane = tid & 63, wid = tid >> 6;
    const int g = lane >> 4, r16 = lane & 15;

    // XCD-chunk swizzle (bijective: 1536 = 8 * 192)
    const int p = blockIdx.x;
    const int logical = (p & 7) * (NBLK / 8) + (p >> 3);
    const int h  = logical % H_;
    const int bn = logical / H_;
    const size_t row0 = (size_t)bn * P_;
    const int m0w = wid * 16;

    // ---------------- phase 1: [Q|K|V](16 rows) = X @ W3head, split bf16 ---
    f32x4 acc[12];
    #pragma unroll
    for (int nf = 0; nf < 12; ++nf) acc[nf] = f32x4{0.f,0.f,0.f,0.f};

    const float* xr0 = x + (row0 + m0w + r16) * C_;
    const char* wbase = (const char*)Wpk + (size_t)h * (KSTEPS * WKS_BYTES);

    // uniform staging: every thread issues exactly one 16B + one 4B load
#define STAGE(ks_, b_) do { \
    const char* _gp = wbase + (size_t)(ks_) * WKS_BYTES; \
    char* _lp = (char*)(sm + (b_) * WKS_U16); \
    GLOAD_LDS16(_gp + tid * 16, _lp + tid * 16); \
    GLOAD_LDS4(_gp + 16384 + tid * 4, _lp + 16384 + tid * 4); \
} while (0)

    f32x4 xr[2][2];
#define XLOAD(ks_, par_) do { \
    const float* _xp = xr0 + (ks_) * 32 + 8 * g; \
    xr[par_][0] = *(const f32x4*)_xp; xr[par_][1] = *(const f32x4*)(_xp + 4); \
} while (0)

    bf16x8 ah, al;
#define SPLIT_A(par_) do { \
    _Pragma("unroll") \
    for (int e = 0; e < 4; ++e) { \
        bf16_t h0 = (bf16_t)xr[par_][0][e], h1 = (bf16_t)xr[par_][1][e]; \
        ah[e]   = h0; al[e]   = (bf16_t)(xr[par_][0][e] - (float)h0); \
        ah[4+e] = h1; al[4+e] = (bf16_t)(xr[par_][1][e] - (float)h1); \
    } } while (0)

    // prologue: stage ks=0,1; x(0). vmcnt(2) leaves only stage(1) in flight.
    STAGE(0, 0);
    XLOAD(0, 0);
    STAGE(1, 1);
    SB();
    asm volatile("s_waitcnt vmcnt(2)" ::: "memory");
    __builtin_amdgcn_s_barrier();
    SB();

    #pragma unroll
    for (int ks = 0; ks < KSTEPS; ++ks) {
        const int par = ks & 1, nxt = par ^ 1;
        if (ks + 2 < KSTEPS) STAGE(ks + 2, (ks + 2) % 3);   // 2 loads
        if (ks + 1 < KSTEPS) XLOAD(ks + 1, nxt);            // 2 loads
        SPLIT_A(par);

        const u16* stg = sm + (ks % 3) * WKS_U16;
        #pragma unroll
        for (int nf = 0; nf < 8; ++nf) {    // Q,K: split 3x
            bf16x8 bh = *(const bf16x8*)&stg[nf * 512 + lane * 8];
            bf16x8 bl = *(const bf16x8*)&stg[6144 + nf * 512 + lane * 8];
            acc[nf] = mfma(ah, bh, acc[nf]);
            acc[nf] = mfma(ah, bl, acc[nf]);
            acc[nf] = mfma(al, bh, acc[nf]);
        }
        #pragma unroll
        for (int nf = 8; nf < 12; ++nf) {   // V: plain
            bf16x8 bh = *(const bf16x8*)&stg[nf * 512 + lane * 8];
            acc[nf] = mfma(ah, bh, acc[nf]);
        }

        if (ks < KSTEPS - 1) {
            // counted drain: allow stage(ks+2) + x(ks+1) (4 youngest) to fly;
            // forces stage(ks+1) complete. Tail ks=10: only x(11) in flight.
            SB();
            if (ks + 2 < KSTEPS) asm volatile("s_waitcnt vmcnt(4)" ::: "memory");
            else                 asm volatile("s_waitcnt vmcnt(2)" ::: "memory");
            __builtin_amdgcn_s_barrier();
            SB();
        } else {
            __syncthreads();   // full drain: stage region reused as Kh/Kl next
        }
    }

    // ---- epilogue: K -> Kh/Kl (split), V -> Vt (b64-packed), swizzled ----
    #pragma unroll
    for (int f = 0; f < 4; ++f) {
        const int d = f * 16 + r16;
        const int q0 = m0w + 4 * g;
        u16x4 vv;
        #pragma unroll
        for (int rr = 0; rr < 4; ++rr) vv[rr] = f2b(acc[8 + f][rr]);
        *(u16x4*)&Vt[d * 256 + (((q0 >> 3) ^ (d & 7)) << 3) + (q0 & 7)] = vv;
        #pragma unroll
        for (int rr = 0; rr < 4; ++rr) {
            int q = q0 + rr;
            int ek = q * 64 + (((d >> 3) ^ (q & 7)) << 3) + (d & 7);
            float kv = acc[4 + f][rr];
            bf16_t khi = (bf16_t)kv;
            Kh[ek] = __builtin_bit_cast(u16, khi);
            Kl[ek] = f2b(kv - (float)khi);
        }
    }

    // ---- Q bounce (per-wave region, two passes hi/lo) ----
    u16* myQb = sm + 49152 + wid * 1024;   // [16][64] swizzled
    bf16x8 aqh[2], aql[2];
    #pragma unroll
    for (int f = 0; f < 4; ++f)
    #pragma unroll
    for (int rr = 0; rr < 4; ++rr) {
        int r = 4 * g + rr;
        int c = f * 16 + r16;
        myQb[r * 64 + (((c >> 3) ^ (r & 7)) << 3) + (c & 7)] = f2b(acc[f][rr]);
    }
    #pragma unroll
    for (int k2 = 0; k2 < 2; ++k2)
        aqh[k2] = *(const bf16x8*)&myQb[r16 * 64 + (((k2 * 4 + g) ^ (r16 & 7)) << 3)];
    SB();   // keep lo-pass writes after hi-pass reads
    #pragma unroll
    for (int f = 0; f < 4; ++f)
    #pragma unroll
    for (int rr = 0; rr < 4; ++rr) {
        int r = 4 * g + rr;
        int c = f * 16 + r16;
        float v = acc[f][rr];
        bf16_t hi = (bf16_t)v;
        myQb[r * 64 + (((c >> 3) ^ (r & 7)) << 3) + (c & 7)] = f2b(v - (float)hi);
    }
    #pragma unroll
    for (int k2 = 0; k2 < 2; ++k2)
        aql[k2] = *(const bf16x8*)&myQb[r16 * 64 + (((k2 * 4 + g) ^ (r16 & 7)) << 3)];

    __syncthreads();   // Kh/Kl/Vt visible block-wide

    // ---------------- phase 2: S^T = K Q^T (swapped operands, split 3x) ----
    // C-layout: lane (g,r16), reg rr holds S[q = m0w+r16][key = 16nf+4g+rr].
    f32x4 S[16];
    #pragma unroll
    for (int nf = 0; nf < 16; ++nf) S[nf] = f32x4{0.f,0.f,0.f,0.f};

    const int kb0 = r16 * 64 + (((0 * 4 + g) ^ (r16 & 7)) << 3);
    const int kb1 = r16 * 64 + (((1 * 4 + g) ^ (r16 & 7)) << 3);

    bf16x8 khv[2][2], klv[2][2];
    {
        khv[0][0] = *(const bf16x8*)&Kh[kb0];
        klv[0][0] = *(const bf16x8*)&Kl[kb0];
        khv[0][1] = *(const bf16x8*)&Kh[kb1];
        klv[0][1] = *(const bf16x8*)&Kl[kb1];
    }
    #pragma unroll
    for (int nf = 0; nf < 16; ++nf) {
        const int par = nf & 1, nxt = par ^ 1;
        if (nf < 15) {
            const int o = (nf + 1) * 1024;
            khv[nxt][0] = *(const bf16x8*)&Kh[o + kb0];
            klv[nxt][0] = *(const bf16x8*)&Kl[o + kb0];
            khv[nxt][1] = *(const bf16x8*)&Kh[o + kb1];
            klv[nxt][1] = *(const bf16x8*)&Kl[o + kb1];
        }
        SB();
        __builtin_amdgcn_s_setprio(1);
        #pragma unroll
        for (int k2 = 0; k2 < 2; ++k2) {
            S[nf] = mfma(khv[par][k2], aqh[k2], S[nf]);   // kh*qh
            S[nf] = mfma(klv[par][k2], aqh[k2], S[nf]);   // kl*qh
            S[nf] = mfma(khv[par][k2], aql[k2], S[nf]);   // kh*ql
        }
        __builtin_amdgcn_s_setprio(0);
        SB();
    }

    // ---------------- softmax: each lane owns one q-row's 64 samples -------
    float inv_;
    {
        float m = -1e30f;
        #pragma unroll
        for (int nf = 0; nf < 16; ++nf)
            #pragma unroll
            for (int rr = 0; rr < 4; ++rr) m = fmaxf(m, S[nf][rr]);
        m = fmaxf(m, __shfl_xor(m, 16, 64));
        m = fmaxf(m, __shfl_xor(m, 32, 64));
        float s = 0.f;
        #pragma unroll
        for (int nf = 0; nf < 16; ++nf)
            #pragma unroll
            for (int rr = 0; rr < 4; ++rr) {
                float pv = __expf((S[nf][rr] - m) * 64.0f);  // scale = D
                S[nf][rr] = pv;
                s += pv;
            }
        s += __shfl_xor(s, 16, 64);
        s += __shfl_xor(s, 32, 64);
        inv_ = 1.0f / s;
    }

    // ---------------- phase 3: O = P V (packed b64 P-bounce) ---------------
    f32x4 O[4];
    #pragma unroll
    for (int f = 0; f < 4; ++f) O[f] = f32x4{0.f,0.f,0.f,0.f};

    u16* pt = sm + 49152 + wid * 1024;       // reuse Q-bounce region: [16][40]
    const int vc = r16 & 7;
    #pragma unroll
    for (int t = 0; t < 8; ++t) {
        bf16x8 bv[4];
        const int vo = (((4 * t + g) ^ vc) << 3) + r16 * 256;
        #pragma unroll
        for (int f = 0; f < 4; ++f)
            bv[f] = *(const bf16x8*)&Vt[f * 4096 + vo];
        #pragma unroll
        for (int nu = 0; nu < 2; ++nu) {
            int nf = 2 * t + nu;
            u16x4 pk;
            #pragma unroll
            for (int rr = 0; rr < 4; ++rr) pk[rr] = f2b(S[nf][rr] * inv_);
            *(u16x4*)&pt[r16 * PB_STRIDE + nu * 16 + 4 * g] = pk;
        }
        bf16x8 ap = *(const bf16x8*)&pt[r16 * PB_STRIDE + 8 * g];
        __builtin_amdgcn_s_setprio(1);
        #pragma unroll
        for (int f = 0; f < 4; ++f) O[f] = mfma(ap, bv[f], O[f]);
        __builtin_amdgcn_s_setprio(0);
    }

    #pragma unroll
    for (int f = 0; f < 4; ++f)
    #pragma unroll
    for (int rr = 0; rr < 4; ++rr)
        attn[(row0 + m0w + 4 * g + rr) * C_ + h * 64 + f * 16 + r16] = f2b(O[f][rr]);
}

// ---------------------------------------------------------------------------
// proj: attn(65536x384 bf16) @ w_proj(384x384) + bias -> f32 out.
// ---------------------------------------------------------------------------
__global__ __launch_bounds__(256, 2) void proj_kernel(
    const u16* __restrict__ attn, const u16* __restrict__ wPt,
    const float* __restrict__ bias, float* __restrict__ out)
{
    __shared__ alignas(16) u16 As[128*32];
    __shared__ alignas(16) u16 Bs[128*32];

    const int tid = threadIdx.x;
    const int lane = tid & 63, wid = tid >> 6;
    const int wr = wid >> 1, wc = wid & 1;
    const int g = lane >> 4, r16 = lane & 15;
    const int m0 = blockIdx.x * 128;
    const int n0 = blockIdx.y * 128;

    f32x4 acc[4][4];
    for (int i = 0; i < 4; i++) for (int j = 0; j < 4; j++) acc[i][j] = f32x4{0.f,0.f,0.f,0.f};

    for (int kt = 0; kt < C_; kt += 32) {
        for (int r = 0; r < 4; ++r) {
            int i = tid + 256*r;
            int mm = i >> 3;
            int kk = (i & 7) << 2;
            u16x4 v = *(const u16x4*)&attn[(size_t)(m0+mm)*C_ + kt + kk];
            int e = mm*32 + (((kk>>3) ^ ((mm>>1)&3))<<3) + (kk&7);
            *(u16x4*)&As[e] = v;
        }
        for (int r = 0; r < 4; ++r) {
            int i = tid + 256*r;
            int nn = i >> 3;
            int kk = (i & 7) << 2;
            u16x4 v = *(const u16x4*)&wPt[(size_t)(n0+nn)*C_ + kt + kk];
            int e = nn*32 + (((kk>>3) ^ ((nn>>1)&3))<<3) + (kk&7);
            *(u16x4*)&Bs[e] = v;
        }
        __syncthreads();

        bf16x8 a[4], b[4];
        for (int i = 0; i < 4; i++) {
            int row = wr*64 + i*16 + r16;
            a[i] = *(const bf16x8*)&As[row*32 + ((g ^ ((row>>1)&3))<<3)];
        }
        for (int j = 0; j < 4; j++) {
            int n = wc*64 + j*16 + r16;
            b[j] = *(const bf16x8*)&Bs[n*32 + ((g ^ ((n>>1)&3))<<3)];
        }
        for (int i = 0; i < 4; i++) for (int j = 0; j < 4; j++)
            acc[i][j] = mfma(a[i], b[j], acc[i][j]);
        __syncthreads();
    }

    for (int i = 0; i < 4; i++) for (int j = 0; j < 4; j++) for (int rr = 0; rr < 4; rr++) {
        size_t row = m0 + wr*64 + i*16 + g*4 + rr;
        int col = n0 + wc*64 + j*16 + r16;
        out[row*C_ + col] = acc[i][j][rr] + bias[col];
    }
}

// ---------------------------------------------------------------------------
extern "C" void kernel_launch(void* const* d_in, const int* in_sizes, int n_in,
                              void* d_out, int out_size, void* d_ws, size_t ws_size,
                              hipStream_t stream)
{
    const float* x      = (const float*)d_in[0];
    const float* w_qkv  = (const float*)d_in[1];
    const float* w_proj = (const float*)d_in[2];
    const float* b_proj = (const float*)d_in[3];
    float* out = (float*)d_out;

    u16* ws = (u16*)d_ws;
    u16* attnb = ws;                                  // 65536*384 u16 = 50 MB
    size_t off = (size_t)M_TOTAL * C_;
    u16* Wpk = ws + off; off += (size_t)H_ * KSTEPS * WKS_U16;
    u16* wPt = ws + off; off += (size_t)C_ * C_;

    hipFuncSetAttribute((const void*)fused_attn,
                        hipFuncAttributeMaxDynamicSharedMemorySize, FUSED_LDS);

    int prep_n = H_ * KSTEPS * 12 * 64 + C_ * C_;
    prep_w<<<dim3((prep_n + 255) / 256), 256, 0, stream>>>(w_qkv, w_proj, Wpk, wPt);
    fused_attn<<<dim3(NBLK), 1024, FUSED_LDS, stream>>>(x, Wpk, attnb);
    proj_kernel<<<dim3(M_TOTAL / 128, C_ / 128), 256, 0, stream>>>(attnb, wPt, b_proj, out);
}